// Round 19
// baseline (108.764 us; speedup 1.0000x reference)
//
#include <hip/hip_runtime.h>
#include <hip/hip_bf16.h>

// Problem constants
#define B_SZ   16384
#define D_SZ   768
#define H_SZ   128
#define S_SZ   65536
#define E_SZ   7

// K layout: [0,768) h_t | [768,896) s_t | [896,1664) h_ctx | 1664..1666 sent | 1667 bias | pad->1696
// N layout: [0,256) r,z summed | [256,384) i_n | [384,512) h_n | [512,519) W_e | 519 W_s | pad->528
// FULLY INDEPENDENT WAVES (no LDS, no barriers): 4096 blocks x 128 thr = 8192 waves.
// Wave (r, f): rowgroup r (16 rows), frag-group f: frags r=f, z=8+f, i_n=16+f, h_n=24+f
// (hidden j in [16f,16f+16)) + heads K-slice (s%8==f). A loaded per-lane direct from HBM
// (A-frag is row-contiguous); siblings share A via same-XCD L2: bid = (r/8)*32 + fp*8 + (r%8)
// -> bid%8 == r%8 for all 4 sibling blocks (8 sibling waves). Heads summed via atomicAdd into
// pre-zeroed out region. Winner-copy appended per block, barrier-free.
#define NFR    33
#define NSTEP  53

typedef __attribute__((ext_vector_type(8))) short bf16x8;
typedef __attribute__((ext_vector_type(4))) float f32x4;

#define LD4(p) (*reinterpret_cast<const float4*>(p))
#define MFMA(d, a, b) d = __builtin_amdgcn_mfma_f32_16x16x32_bf16(a, b, d, 0, 0, 0)

static __device__ __forceinline__ ushort f2bf(float v) {
    unsigned u = __float_as_uint(v);
    u = (u + 0x7FFFu + ((u >> 16) & 1u)) >> 16;   // RNE (pack kernel / tail only)
    return (ushort)u;
}

static __device__ __forceinline__ unsigned pk2(float x, float y) {
    unsigned a = __float_as_uint(x) + 0x8000u;
    unsigned b = __float_as_uint(y) + 0x8000u;
    return __builtin_amdgcn_perm(b, a, 0x07060302);   // [a.hi16 | b.hi16]
}

static __device__ __forceinline__ bf16x8 cvt8(float4 a, float4 b) {
    union { unsigned u[4]; bf16x8 v; } r;
    r.u[0] = pk2(a.x, a.y); r.u[1] = pk2(a.z, a.w);
    r.u[2] = pk2(b.x, b.y); r.u[3] = pk2(b.z, b.w);
    return r.v;
}

// logical packed-weight value at (n, k)
static __device__ __forceinline__ float w2_value(int n, int k,
    const float* __restrict__ W_ih, const float* __restrict__ W_hh,
    const float* __restrict__ b_ih, const float* __restrict__ b_hh,
    const float* __restrict__ W_e,  const float* __restrict__ b_e,
    const float* __restrict__ W_s,  const float* __restrict__ b_s)
{
    float v = 0.0f;
    if (n < 256) {
        if (k < 768)                        v = W_ih[(size_t)n * 771 + k];
        else if (k < 896)                   v = W_hh[(size_t)n * 128 + (k - 768)];
        else if (k >= 1664 && k < 1667)     v = W_ih[(size_t)n * 771 + 768 + (k - 1664)];
        else if (k == 1667)                 v = b_ih[n] + b_hh[n];
    } else if (n < 384) {
        if (k < 768)                        v = W_ih[(size_t)n * 771 + k];
        else if (k >= 1664 && k < 1667)     v = W_ih[(size_t)n * 771 + 768 + (k - 1664)];
        else if (k == 1667)                 v = b_ih[n];
    } else if (n < 512) {
        int g = n - 128;
        if (k >= 768 && k < 896)            v = W_hh[(size_t)g * 128 + (k - 768)];
        else if (k == 1667)                 v = b_hh[g];
    } else if (n < 520) {
        int e = n - 512;
        const float* Wr = (e < E_SZ) ? (W_e + (size_t)e * 1667) : W_s;
        if (k < 768)                        v = Wr[k];
        else if (k < 896)                   v = Wr[771 + (k - 768)];
        else if (k < 1664)                  v = Wr[899 + (k - 896)];
        else if (k < 1667)                  v = Wr[768 + (k - 1664)];
        else if (k == 1667)                 v = (e < E_SZ) ? b_e[e] : b_s[0];
    }
    return v;
}

// ---------------- pack W2 frag-major: W2f[(nf*NSTEP + kstep)*64 + lane][8] ----------------
__global__ __launch_bounds__(256) void pack_w2f_kernel(
    const float* __restrict__ W_ih, const float* __restrict__ W_hh,
    const float* __restrict__ b_ih, const float* __restrict__ b_hh,
    const float* __restrict__ W_e,  const float* __restrict__ b_e,
    const float* __restrict__ W_s,  const float* __restrict__ b_s,
    ushort* __restrict__ W2f)
{
    int tid = blockIdx.x * 256 + threadIdx.x;
    if (tid >= NFR * NSTEP * 64) return;
    int lane  = tid & 63;
    int kstep = (tid >> 6) % NSTEP;
    int nf    = tid / (NSTEP * 64);
    int n     = nf * 16 + (lane & 15);
    int kbase = kstep * 32 + (lane >> 4) * 8;
    ushort o[8];
#pragma unroll
    for (int j = 0; j < 8; ++j)
        o[j] = f2bf(w2_value(n, kbase + j, W_ih, W_hh, b_ih, b_hh, W_e, b_e, W_s, b_s));
    *reinterpret_cast<uint4*>(W2f + (size_t)tid * 8) = *reinterpret_cast<const uint4*>(o);
}

// ---------------- winner (last-write-wins) ----------------
__global__ __launch_bounds__(256) void winner_kernel(const int* __restrict__ slot_ids,
                                                     int* __restrict__ winner)
{
    int b = blockIdx.x * 256 + threadIdx.x;
    if (b < B_SZ) atomicMax(&winner[slot_ids[b]], b);
}

static __device__ __forceinline__ bf16x8 ldB(const ushort* __restrict__ W2f, int nf, int ks, int lane) {
    return *reinterpret_cast<const bf16x8*>(W2f + ((size_t)(nf * NSTEP + ks) * 64 + lane) * 8);
}

// ---------------- fused kernel: independent waves, no LDS, no barriers ----------------
__global__ __launch_bounds__(128, 8) void fused_kernel(
    const float* __restrict__ h_t,   const float* __restrict__ h_ctx,
    const float* __restrict__ sent,  const int* __restrict__ slot_ids,
    const float* __restrict__ memory,const ushort* __restrict__ W2f,
    const int* __restrict__ winner,
    float* __restrict__ out_emo, float* __restrict__ out_shift, float* __restrict__ out_mem)
{
    const int tid  = threadIdx.x;
    const int wave = tid >> 6;
    const int lane = tid & 63;
    const int bid  = blockIdx.x;
    // same-XCD sibling mapping: bid%8 == r%8 for all frag-groups of rowgroup r
    const int r    = ((bid >> 5) << 3) | (bid & 7);          // 0..1023
    const int f    = (((bid >> 3) & 3) << 1) | wave;         // 0..7
    const int row0 = r * 16;
    const int cl   = lane & 15, kg = lane >> 4;
    const int rowA = row0 + cl;
    const int slotA = slot_ids[rowA];

    f32x4 z4 = {0.f, 0.f, 0.f, 0.f};
    f32x4 aR = z4, aZ = z4, aI = z4, aH = z4, hc = z4;

    // ---- h_t: steps 0..23 (frags r, z, i_n; heads at s%8==f) ----
    {
        const float* pA = h_t + (size_t)rowA * D_SZ + kg * 8;
#pragma unroll
        for (int s = 0; s < 24; ++s) {
            bf16x8 B0 = ldB(W2f, f, s, lane);
            bf16x8 B1 = ldB(W2f, 8 + f, s, lane);
            bf16x8 B2 = ldB(W2f, 16 + f, s, lane);
            float4 x0 = LD4(pA + s * 32), x1 = LD4(pA + s * 32 + 4);
            bf16x8 a0 = cvt8(x0, x1);
            MFMA(aR, a0, B0); MFMA(aZ, a0, B1); MFMA(aI, a0, B2);
            if ((s & 7) == f) {
                bf16x8 Bh = ldB(W2f, 32, s, lane);
                MFMA(hc, a0, Bh);
            }
        }
    }
    // ---- s_t: steps 24..27 (frags r, z, h_n; heads at s%8==f -> f<4) ----
    {
        const float* pM = memory + (size_t)slotA * H_SZ + kg * 8;
#pragma unroll
        for (int t = 0; t < 4; ++t) {
            const int s = 24 + t;
            bf16x8 B0 = ldB(W2f, f, s, lane);
            bf16x8 B1 = ldB(W2f, 8 + f, s, lane);
            bf16x8 B2 = ldB(W2f, 24 + f, s, lane);
            float4 x0 = LD4(pM + t * 32), x1 = LD4(pM + t * 32 + 4);
            bf16x8 a0 = cvt8(x0, x1);
            MFMA(aR, a0, B0); MFMA(aZ, a0, B1); MFMA(aH, a0, B2);
            if (t == f) {
                bf16x8 Bh = ldB(W2f, 32, s, lane);
                MFMA(hc, a0, Bh);
            }
        }
    }
    // ---- h_ctx: only owned heads steps (s%8==f, 28<=s<52) — partitioned, read once ----
    {
        const float* pC = h_ctx + (size_t)rowA * D_SZ + kg * 8;
        const int s0 = (f < 4) ? (32 + f) : (24 + f);
#pragma unroll 3
        for (int s = s0; s < 52; s += 8) {
            bf16x8 Bh = ldB(W2f, 32, s, lane);
            float4 x0 = LD4(pC + (s - 28) * 32), x1 = LD4(pC + (s - 28) * 32 + 4);
            MFMA(hc, cvt8(x0, x1), Bh);
        }
    }
    // ---- tail step 52: sent(3) + bias-one + zeros (all 4 frags; heads if f==4) ----
    {
        bf16x8 a0;
#pragma unroll
        for (int jj = 0; jj < 8; ++jj) {
            int kk = kg * 8 + jj;
            float v0 = 0.f;
            if (kk < 3)       v0 = sent[(size_t)rowA * 3 + kk];
            else if (kk == 3) v0 = 1.f;
            a0[jj] = (short)f2bf(v0);
        }
        bf16x8 T0 = ldB(W2f, f, 52, lane),      T1 = ldB(W2f, 8 + f, 52, lane);
        bf16x8 T2 = ldB(W2f, 16 + f, 52, lane), T3 = ldB(W2f, 24 + f, 52, lane);
        MFMA(aR, a0, T0); MFMA(aZ, a0, T1); MFMA(aI, a0, T2); MFMA(aH, a0, T3);
        if (f == 4) {   // 52 % 8 == 4
            bf16x8 Bh = ldB(W2f, 32, 52, lane);
            MFMA(hc, a0, Bh);
        }
    }

    // ---- wave-local GRU + winner scatter for hidden j = 16f + cl ----
    const int j = 16 * f + cl;
#pragma unroll
    for (int rr = 0; rr < 4; ++rr) {
        const int row  = row0 + kg * 4 + rr;
        const int slot = slot_ids[row];
        const bool win = (winner[slot] == row);
        float rg  = aR[rr];
        float zg  = aZ[rr];
        float inn = aI[rr];
        float hnn = aH[rr];
        rg = 1.0f / (1.0f + __expf(-rg));
        zg = 1.0f / (1.0f + __expf(-zg));
        float nn = tanhf(inn + rg * hnn);
        float h  = memory[(size_t)slot * H_SZ + j];   // exact f32 pre-update state
        float sn = (1.0f - zg) * nn + zg * h;
        if (win) out_mem[(size_t)slot * H_SZ + j] = sn;
        // heads partial: D-layout col = lane&15 = output index; row = kg*4 + rr
        float hv = hc[rr];
        if (cl < E_SZ)       atomicAdd(out_emo + (size_t)row * E_SZ + cl, hv);
        else if (cl == E_SZ) atomicAdd(out_shift + row, hv);
    }

    // ---- winner-aware base copy: this block owns slots [bid*16, bid*16+16) ----
#pragma unroll
    for (int k = 0; k < 4; ++k) {
        int idx  = k * 128 + tid;            // 0..511
        int sr   = idx >> 5;                 // 0..15
        int c4   = (idx & 31) * 4;           // 0..124
        int slot = bid * 16 + sr;
        if (winner[slot] < 0) {
            float4 v = LD4(memory + (size_t)slot * H_SZ + c4);
            *reinterpret_cast<float4*>(out_mem + (size_t)slot * H_SZ + c4) = v;
        }
    }
}

// ---------------- launch ----------------
extern "C" void kernel_launch(void* const* d_in, const int* in_sizes, int n_in,
                              void* d_out, int out_size, void* d_ws, size_t ws_size,
                              hipStream_t stream)
{
    const float* h_t     = (const float*)d_in[0];
    const float* h_ctx   = (const float*)d_in[1];
    const float* sent    = (const float*)d_in[2];
    const int*   slot_ids= (const int*)  d_in[3];
    const float* memory  = (const float*)d_in[4];
    const float* W_ih    = (const float*)d_in[5];
    const float* W_hh    = (const float*)d_in[6];
    const float* b_ih    = (const float*)d_in[7];
    const float* b_hh    = (const float*)d_in[8];
    const float* W_e     = (const float*)d_in[9];
    const float* b_e     = (const float*)d_in[10];
    const float* W_s     = (const float*)d_in[11];
    const float* b_s     = (const float*)d_in[12];

    float* out       = (float*)d_out;
    float* out_emo   = out;                                    // [B,7]
    float* out_shift = out + (size_t)B_SZ * E_SZ;              // [B]
    float* out_mem   = out + (size_t)B_SZ * E_SZ + B_SZ;       // [S,H]

    int*    winner = (int*)d_ws;                               // S ints
    ushort* W2f    = (ushort*)((char*)d_ws + (size_t)S_SZ * sizeof(int));

    hipMemsetAsync(winner, 0xFF, (size_t)S_SZ * sizeof(int), stream);          // -1
    hipMemsetAsync(out, 0, (size_t)B_SZ * (E_SZ + 1) * sizeof(float), stream); // heads accum zero

    pack_w2f_kernel<<<(NFR * NSTEP * 64 + 255) / 256, 256, 0, stream>>>(
        W_ih, W_hh, b_ih, b_hh, W_e, b_e, W_s, b_s, W2f);
    winner_kernel<<<B_SZ / 256, 256, 0, stream>>>(slot_ids, winner);
    fused_kernel<<<4096, 128, 0, stream>>>(
        h_t, h_ctx, sent, slot_ids, memory, W2f, winner, out_emo, out_shift, out_mem);
}

// Round 21
// 91.648 us; speedup vs baseline: 1.1868x; 1.1868x over previous
//
#include <hip/hip_runtime.h>
#include <hip/hip_bf16.h>

// Problem constants
#define B_SZ   16384
#define D_SZ   768
#define H_SZ   128
#define S_SZ   65536
#define E_SZ   7

// K layout: [0,768) h_t | [768,896) s_t | [896,1664) h_ctx | 1664..1666 sent | 1667 bias | pad->1696
// N layout: [0,256) r,z summed | [256,384) i_n | [384,512) h_n | [512,519) W_e | 519 W_s | pad->528
// M=16 per block, 1024 blocks, 512 threads = 8 waves ALL compute. Wave w owns hidden j in
// [16w,16w+16): frags r=w, z=8+w, i_n=16+w, h_n=24+w -> wave-local GRU; acc = 4 f32x4 (16 VGPR).
// Heads (frag 32) K-split by (s mod 8)==w. A staged in 8-step chunks (16 KB) via global_load_lds,
// double-buffered; LDS 40 KB -> 4 blocks/CU -> 32 waves/CU.
// ROUND 21 (= round 20 with compile fix): NON-TEMPORAL cache policy on all streaming accesses
// (A-stage DMAs aux=2, winner-copy NT via u32x4) so the 1.8 MB W2f table stays L2-resident —
// the 4300-cy/step invariant across rounds 12-19 matches B loads missing L2 due to stream eviction.
#define NFR    33
#define NSTEP  53

typedef __attribute__((ext_vector_type(8))) short bf16x8;
typedef __attribute__((ext_vector_type(4))) float f32x4;
typedef __attribute__((ext_vector_type(4))) unsigned int u32x4;

#define LD4(p) (*reinterpret_cast<const float4*>(p))
#define MFMA(d, a, b) d = __builtin_amdgcn_mfma_f32_16x16x32_bf16(a, b, d, 0, 0, 0)

// async global->LDS DMA, 16B/lane; aux: 0 = normal, 2 = NT (non-temporal, evict-first)
#define GLDS(gp, lp) __builtin_amdgcn_global_load_lds(                              \
        (const __attribute__((address_space(1))) unsigned int*)(gp),                \
        (__attribute__((address_space(3))) unsigned int*)(lp), 16, 0, 0)
#define GLDSN(gp, lp) __builtin_amdgcn_global_load_lds(                             \
        (const __attribute__((address_space(1))) unsigned int*)(gp),                \
        (__attribute__((address_space(3))) unsigned int*)(lp), 16, 0, 2)

static __device__ __forceinline__ ushort f2bf(float v) {
    unsigned u = __float_as_uint(v);
    u = (u + 0x7FFFu + ((u >> 16) & 1u)) >> 16;   // RNE (pack kernel / tail only)
    return (ushort)u;
}

static __device__ __forceinline__ unsigned pk2(float x, float y) {
    unsigned a = __float_as_uint(x) + 0x8000u;
    unsigned b = __float_as_uint(y) + 0x8000u;
    return __builtin_amdgcn_perm(b, a, 0x07060302);   // [a.hi16 | b.hi16]
}

static __device__ __forceinline__ bf16x8 cvt8(float4 a, float4 b) {
    union { unsigned u[4]; bf16x8 v; } r;
    r.u[0] = pk2(a.x, a.y); r.u[1] = pk2(a.z, a.w);
    r.u[2] = pk2(b.x, b.y); r.u[3] = pk2(b.z, b.w);
    return r.v;
}

// logical packed-weight value at (n, k)
static __device__ __forceinline__ float w2_value(int n, int k,
    const float* __restrict__ W_ih, const float* __restrict__ W_hh,
    const float* __restrict__ b_ih, const float* __restrict__ b_hh,
    const float* __restrict__ W_e,  const float* __restrict__ b_e,
    const float* __restrict__ W_s,  const float* __restrict__ b_s)
{
    float v = 0.0f;
    if (n < 256) {
        if (k < 768)                        v = W_ih[(size_t)n * 771 + k];
        else if (k < 896)                   v = W_hh[(size_t)n * 128 + (k - 768)];
        else if (k >= 1664 && k < 1667)     v = W_ih[(size_t)n * 771 + 768 + (k - 1664)];
        else if (k == 1667)                 v = b_ih[n] + b_hh[n];
    } else if (n < 384) {
        if (k < 768)                        v = W_ih[(size_t)n * 771 + k];
        else if (k >= 1664 && k < 1667)     v = W_ih[(size_t)n * 771 + 768 + (k - 1664)];
        else if (k == 1667)                 v = b_ih[n];
    } else if (n < 512) {
        int g = n - 128;
        if (k >= 768 && k < 896)            v = W_hh[(size_t)g * 128 + (k - 768)];
        else if (k == 1667)                 v = b_hh[g];
    } else if (n < 520) {
        int e = n - 512;
        const float* Wr = (e < E_SZ) ? (W_e + (size_t)e * 1667) : W_s;
        if (k < 768)                        v = Wr[k];
        else if (k < 896)                   v = Wr[771 + (k - 768)];
        else if (k < 1664)                  v = Wr[899 + (k - 896)];
        else if (k < 1667)                  v = Wr[768 + (k - 1664)];
        else if (k == 1667)                 v = (e < E_SZ) ? b_e[e] : b_s[0];
    }
    return v;
}

// ---------------- pack W2 frag-major: W2f[(nf*NSTEP + kstep)*64 + lane][8] ----------------
__global__ __launch_bounds__(256) void pack_w2f_kernel(
    const float* __restrict__ W_ih, const float* __restrict__ W_hh,
    const float* __restrict__ b_ih, const float* __restrict__ b_hh,
    const float* __restrict__ W_e,  const float* __restrict__ b_e,
    const float* __restrict__ W_s,  const float* __restrict__ b_s,
    ushort* __restrict__ W2f)
{
    int tid = blockIdx.x * 256 + threadIdx.x;
    if (tid >= NFR * NSTEP * 64) return;
    int lane  = tid & 63;
    int kstep = (tid >> 6) % NSTEP;
    int nf    = tid / (NSTEP * 64);
    int n     = nf * 16 + (lane & 15);
    int kbase = kstep * 32 + (lane >> 4) * 8;
    ushort o[8];
#pragma unroll
    for (int j = 0; j < 8; ++j)
        o[j] = f2bf(w2_value(n, kbase + j, W_ih, W_hh, b_ih, b_hh, W_e, b_e, W_s, b_s));
    *reinterpret_cast<uint4*>(W2f + (size_t)tid * 8) = *reinterpret_cast<const uint4*>(o);
}

// ---------------- winner (last-write-wins) ----------------
__global__ __launch_bounds__(256) void winner_kernel(const int* __restrict__ slot_ids,
                                                     int* __restrict__ winner)
{
    int b = blockIdx.x * 256 + threadIdx.x;
    if (b < B_SZ) atomicMax(&winner[slot_ids[b]], b);
}

static __device__ __forceinline__ bf16x8 ldB(const ushort* __restrict__ W2f, int nf, int ks, int lane) {
    return *reinterpret_cast<const bf16x8*>(W2f + ((size_t)(nf * NSTEP + ks) * 64 + lane) * 8);
}

// LDS A read: 8-step panel of [16 rows][128 B], XOR-swizzled (matches pre-swizzled DMA source)
static __device__ __forceinline__ float4 lds_rd(const char* Ab, int st, int row, int h) {
    return *reinterpret_cast<const float4*>(Ab + st * 2048 + row * 128 + ((h ^ (row & 7)) << 4));
}

// h_t chunk (8 steps): frags r=W, z=8+W, i_n=16+W; heads at st == W
template<int W>
static __device__ __forceinline__ void chunk_ht8(int c, const char* Ab, int lane,
                                                 const ushort* __restrict__ W2f,
                                                 f32x4* __restrict__ acc, f32x4* __restrict__ hacc)
{
    const int cl = lane & 15, kg = lane >> 4;
#pragma unroll
    for (int st = 0; st < 8; ++st) {
        const int s = c * 8 + st;
        bf16x8 B0 = ldB(W2f, W, s, lane), B1 = ldB(W2f, 8 + W, s, lane), B2 = ldB(W2f, 16 + W, s, lane);
        float4 x0 = lds_rd(Ab, st, cl, 2 * kg), x1 = lds_rd(Ab, st, cl, 2 * kg + 1);
        bf16x8 a0 = cvt8(x0, x1);
        MFMA(acc[0], a0, B0); MFMA(acc[1], a0, B1); MFMA(acc[2], a0, B2);
        if (st == W) {
            bf16x8 Bh = ldB(W2f, 32, s, lane);
            MFMA(hacc[0], a0, Bh);
        }
    }
}

// chunk 3: slots 0-3 = s_t steps 24-27 (r, z, h_n; heads for W<4 at t==W);
//          slots 4-7 = ctx steps 28-31 (heads only; wave W>=4 handles slot W)
template<int W>
static __device__ __forceinline__ void chunk_c3(const char* Ab, int lane,
                                                const ushort* __restrict__ W2f,
                                                f32x4* __restrict__ acc, f32x4* __restrict__ hacc)
{
    const int cl = lane & 15, kg = lane >> 4;
#pragma unroll
    for (int t = 0; t < 4; ++t) {
        const int s = 24 + t;
        bf16x8 B0 = ldB(W2f, W, s, lane), B1 = ldB(W2f, 8 + W, s, lane), B2 = ldB(W2f, 24 + W, s, lane);
        float4 x0 = lds_rd(Ab, t, cl, 2 * kg), x1 = lds_rd(Ab, t, cl, 2 * kg + 1);
        bf16x8 a0 = cvt8(x0, x1);
        MFMA(acc[0], a0, B0); MFMA(acc[1], a0, B1); MFMA(acc[3], a0, B2);
        if constexpr (W < 4) {
            if (t == W) {
                bf16x8 Bh = ldB(W2f, 32, s, lane);
                MFMA(hacc[0], a0, Bh);
            }
        }
    }
    if constexpr (W >= 4) {          // ctx step s = 24+W (28..31), lds slot W
        bf16x8 Bh = ldB(W2f, 32, 24 + W, lane);
        float4 x0 = lds_rd(Ab, W, cl, 2 * kg), x1 = lds_rd(Ab, W, cl, 2 * kg + 1);
        MFMA(hacc[0], cvt8(x0, x1), Bh);
    }
}

// ctx chunk (8 steps): wave W handles lds slot W, step s = sbase + W
template<int W>
static __device__ __forceinline__ void ctx_chunk8(int sbase, const char* Ab, int lane,
                                                  const ushort* __restrict__ W2f,
                                                  f32x4* __restrict__ hacc)
{
    const int cl = lane & 15, kg = lane >> 4;
    bf16x8 Bh = ldB(W2f, 32, sbase + W, lane);
    float4 x0 = lds_rd(Ab, W, cl, 2 * kg), x1 = lds_rd(Ab, W, cl, 2 * kg + 1);
    MFMA(hacc[0], cvt8(x0, x1), Bh);
}

// ctx chunk 6 (4 steps 48-51): waves 0-3 only
template<int W>
static __device__ __forceinline__ void ctx_chunk4(const char* Ab, int lane,
                                                  const ushort* __restrict__ W2f,
                                                  f32x4* __restrict__ hacc)
{
    if constexpr (W < 4) {
        const int cl = lane & 15, kg = lane >> 4;
        bf16x8 Bh = ldB(W2f, 32, 48 + W, lane);
        float4 x0 = lds_rd(Ab, W, cl, 2 * kg), x1 = lds_rd(Ab, W, cl, 2 * kg + 1);
        MFMA(hacc[0], cvt8(x0, x1), Bh);
    }
}

// tail step 52 + wave-local GRU epilogue
template<int W>
static __device__ __forceinline__ void tail_and_gru(
    const float* __restrict__ sent, const float* __restrict__ memory,
    const int* __restrict__ slot_ids, const int* __restrict__ winner,
    int row0, int lane, const ushort* __restrict__ W2f,
    f32x4* __restrict__ acc, f32x4* __restrict__ hacc, float* __restrict__ out_mem)
{
    const int cl = lane & 15, kg = lane >> 4;
    // tail (k=1664..1695): sent(3) + bias-one + zeros
    {
        const int rA0 = row0 + cl;
        bf16x8 a0;
#pragma unroll
        for (int jj = 0; jj < 8; ++jj) {
            int kk = kg * 8 + jj;
            float v0 = 0.f;
            if (kk < 3)       v0 = sent[(size_t)rA0 * 3 + kk];
            else if (kk == 3) v0 = 1.f;
            a0[jj] = (short)f2bf(v0);
        }
        bf16x8 T0 = ldB(W2f, W, 52, lane),      T1 = ldB(W2f, 8 + W, 52, lane);
        bf16x8 T2 = ldB(W2f, 16 + W, 52, lane), T3 = ldB(W2f, 24 + W, 52, lane);
        MFMA(acc[0], a0, T0); MFMA(acc[1], a0, T1);
        MFMA(acc[2], a0, T2); MFMA(acc[3], a0, T3);
        if constexpr (W == 4) {   // step 52: (52&7)==4
            bf16x8 Bh = ldB(W2f, 32, 52, lane);
            MFMA(hacc[0], a0, Bh);
        }
    }
    // wave-local GRU + winner scatter for hidden j = 16W + cl
    const int j = 16 * W + cl;
#pragma unroll
    for (int rr = 0; rr < 4; ++rr) {
        const int row  = row0 + kg * 4 + rr;
        const int slot = slot_ids[row];
        const bool win = (winner[slot] == row);
        float rgate = acc[0][rr];
        float zg    = acc[1][rr];
        float inn   = acc[2][rr];
        float hnn   = acc[3][rr];
        rgate = 1.0f / (1.0f + __expf(-rgate));
        zg    = 1.0f / (1.0f + __expf(-zg));
        float nn = tanhf(inn + rgate * hnn);
        float h  = memory[(size_t)slot * H_SZ + j];   // exact f32 pre-update state
        float sn = (1.0f - zg) * nn + zg * h;
        if (win) out_mem[(size_t)slot * H_SZ + j] = sn;
    }
}

// ---------------- fused kernel: M=16, 8 waves all-compute, 4 blocks/CU ----------------
__global__ __launch_bounds__(512, 8) void fused_kernel(
    const float* __restrict__ h_t,   const float* __restrict__ h_ctx,
    const float* __restrict__ sent,  const int* __restrict__ slot_ids,
    const float* __restrict__ memory,const ushort* __restrict__ W2f,
    const int* __restrict__ winner,
    float* __restrict__ out_emo, float* __restrict__ out_shift, float* __restrict__ out_mem)
{
    __shared__ alignas(16) char  A_st[2][8 * 2048];   // 32 KB: 2 bufs x 8 steps x [16 rows][128 B]
    __shared__ alignas(16) f32x4 redh[8 * 64];        // 8 KB heads partials

    const int tid  = threadIdx.x;
    const int wave = tid >> 6;
    const int lane = tid & 63;
    const int row0 = blockIdx.x * 16;

    // staging identity: unit covers (st = round*4 + (wave>>1), w128 = (wave&1)*64 + lane);
    // row = w128>>3 (0..15), cg pre-swizzled.
    const int srow  = (tid & 127) >> 3;
    const int scg   = (lane & 7) ^ (srow & 7);
    const int sbh   = (wave & 1) * 1024;        // half-panel base within a step
    const int sst0  = wave >> 1;                // round-0 step (0..3); round-1 adds 4
    const int sslot = slot_ids[row0 + srow];

    f32x4 acc[4], hacc[1];
    {
        f32x4 z = {0.f, 0.f, 0.f, 0.f};
#pragma unroll
        for (int i = 0; i < 4; ++i) acc[i] = z;
        hacc[0] = z;
    }

#define STAGE_HT8(BUF, S0) do { _Pragma("unroll")                                         \
    for (int rd = 0; rd < 2; ++rd) { int stp = rd * 4 + sst0;                             \
        GLDSN(h_t + (size_t)(row0 + srow) * D_SZ + ((S0) + stp) * 32 + scg * 4,           \
              &A_st[BUF][stp * 2048 + sbh]); } } while (0)

#define STAGE_MEMCTX(BUF) do { _Pragma("unroll")                                          \
    for (int rd = 0; rd < 2; ++rd) { int stp = rd * 4 + sst0;                             \
        if (stp < 4) GLDS(memory + (size_t)sslot * H_SZ + stp * 32 + scg * 4,             \
                          &A_st[BUF][stp * 2048 + sbh]);                                  \
        else GLDSN(h_ctx + (size_t)(row0 + srow) * D_SZ + (stp - 4) * 32 + scg * 4,       \
                   &A_st[BUF][stp * 2048 + sbh]); } } while (0)

#define STAGE_CTX8(BUF, X0) do { _Pragma("unroll")                                        \
    for (int rd = 0; rd < 2; ++rd) { int stp = rd * 4 + sst0;                             \
        GLDSN(h_ctx + (size_t)(row0 + srow) * D_SZ + ((X0) + stp) * 32 + scg * 4,         \
              &A_st[BUF][stp * 2048 + sbh]); } } while (0)

#define STAGE_CTX4(BUF, X0) do { int stp = sst0;                                          \
        GLDSN(h_ctx + (size_t)(row0 + srow) * D_SZ + ((X0) + stp) * 32 + scg * 4,         \
              &A_st[BUF][stp * 2048 + sbh]); } while (0)

#define COPYSL(I0, N) do {                                                                \
    for (int k = 0; k < (N); ++k) {                                                       \
        int idx  = ((I0) + k) * 512 + tid;       /* 0..2047 over 4 rounds */              \
        int rr   = idx >> 5;                     /* slot row 0..63 */                     \
        int c4   = (idx & 31) * 4;                                                        \
        int slot = blockIdx.x * 64 + rr;                                                  \
        if (winner[slot] < 0) {                                                           \
            u32x4 v = __builtin_nontemporal_load(                                         \
                reinterpret_cast<const u32x4*>(memory + (size_t)slot * H_SZ + c4));       \
            __builtin_nontemporal_store(v,                                                \
                reinterpret_cast<u32x4*>(out_mem + (size_t)slot * H_SZ + c4));            \
        } } } while (0)

#define BYWAVE(...) do { switch (wave) {                                                  \
    case 0: { constexpr int W = 0; __VA_ARGS__; } break;                                  \
    case 1: { constexpr int W = 1; __VA_ARGS__; } break;                                  \
    case 2: { constexpr int W = 2; __VA_ARGS__; } break;                                  \
    case 3: { constexpr int W = 3; __VA_ARGS__; } break;                                  \
    case 4: { constexpr int W = 4; __VA_ARGS__; } break;                                  \
    case 5: { constexpr int W = 5; __VA_ARGS__; } break;                                  \
    case 6: { constexpr int W = 6; __VA_ARGS__; } break;                                  \
    default:{ constexpr int W = 7; __VA_ARGS__; } break; } } while (0)

    // prologue: stage chunk 0 (h_t steps 0-7)
    STAGE_HT8(0, 0);
    __syncthreads();

    // iter 0: compute c0 (buf0); stage c1 (h_t 8-15 -> buf1)
    BYWAVE(chunk_ht8<W>(0, A_st[0], lane, W2f, acc, hacc));
    COPYSL(0, 1);
    STAGE_HT8(1, 8);
    __syncthreads();

    // iter 1: c1 (buf1); stage c2 (h_t 16-23 -> buf0)
    BYWAVE(chunk_ht8<W>(1, A_st[1], lane, W2f, acc, hacc));
    COPYSL(1, 1);
    STAGE_HT8(0, 16);
    __syncthreads();

    // iter 2: c2 (buf0); stage c3 (s_t + ctx 28-31 -> buf1)
    BYWAVE(chunk_ht8<W>(2, A_st[0], lane, W2f, acc, hacc));
    COPYSL(2, 1);
    STAGE_MEMCTX(1);
    __syncthreads();

    // iter 3: c3 (buf1); stage c4 (ctx 32-39 -> buf0)
    BYWAVE(chunk_c3<W>(A_st[1], lane, W2f, acc, hacc));
    COPYSL(3, 1);
    STAGE_CTX8(0, 4);
    __syncthreads();

    // iter 4: c4 (buf0, s=32-39); stage c5 (ctx 40-47 -> buf1)
    BYWAVE(ctx_chunk8<W>(32, A_st[0], lane, W2f, hacc));
    STAGE_CTX8(1, 12);
    __syncthreads();

    // iter 5: c5 (buf1, s=40-47); stage c6 (ctx 48-51 -> buf0)
    BYWAVE(ctx_chunk8<W>(40, A_st[1], lane, W2f, hacc));
    STAGE_CTX4(0, 20);
    __syncthreads();

    // iter 6: c6 (buf0, s=48-51) + tail + wave-local GRU
    BYWAVE((ctx_chunk4<W>(A_st[0], lane, W2f, hacc),
            tail_and_gru<W>(sent, memory, slot_ids, winner, row0, lane, W2f,
                            acc, hacc, out_mem)));

    // heads outputs: LDS reduction over 8 waves
    __syncthreads();
    redh[wave * 64 + lane] = hacc[0];
    __syncthreads();
    if (tid < 64) {
        f32x4 hv = redh[tid];
#pragma unroll
        for (int w = 1; w < 8; ++w) hv += redh[w * 64 + tid];
        const int col  = tid & 15;
        const int rowb = row0 + (tid >> 4) * 4;
#pragma unroll
        for (int rr = 0; rr < 4; ++rr) {
            const int row = rowb + rr;
            if (col < E_SZ)       out_emo[(size_t)row * E_SZ + col] = hv[rr];
            else if (col == E_SZ) out_shift[row] = hv[rr];
        }
    }
#undef STAGE_HT8
#undef STAGE_MEMCTX
#undef STAGE_CTX8
#undef STAGE_CTX4
#undef COPYSL
#undef BYWAVE
}

// ---------------- launch ----------------
extern "C" void kernel_launch(void* const* d_in, const int* in_sizes, int n_in,
                              void* d_out, int out_size, void* d_ws, size_t ws_size,
                              hipStream_t stream)
{
    const float* h_t     = (const float*)d_in[0];
    const float* h_ctx   = (const float*)d_in[1];
    const float* sent    = (const float*)d_in[2];
    const int*   slot_ids= (const int*)  d_in[3];
    const float* memory  = (const float*)d_in[4];
    const float* W_ih    = (const float*)d_in[5];
    const float* W_hh    = (const float*)d_in[6];
    const float* b_ih    = (const float*)d_in[7];
    const float* b_hh    = (const float*)d_in[8];
    const float* W_e     = (const float*)d_in[9];
    const float* b_e     = (const float*)d_in[10];
    const float* W_s     = (const float*)d_in[11];
    const float* b_s     = (const float*)d_in[12];

    float* out       = (float*)d_out;
    float* out_emo   = out;                                    // [B,7]
    float* out_shift = out + (size_t)B_SZ * E_SZ;              // [B]
    float* out_mem   = out + (size_t)B_SZ * E_SZ + B_SZ;       // [S,H]

    int*    winner = (int*)d_ws;                               // S ints
    ushort* W2f    = (ushort*)((char*)d_ws + (size_t)S_SZ * sizeof(int));

    hipMemsetAsync(winner, 0xFF, (size_t)S_SZ * sizeof(int), stream);   // -1

    pack_w2f_kernel<<<(NFR * NSTEP * 64 + 255) / 256, 256, 0, stream>>>(
        W_ih, W_hh, b_ih, b_hh, W_e, b_e, W_s, b_s, W2f);
    winner_kernel<<<B_SZ / 256, 256, 0, stream>>>(slot_ids, winner);
    fused_kernel<<<B_SZ / 16, 512, 0, stream>>>(
        h_t, h_ctx, sent, slot_ids, memory, W2f, winner, out_emo, out_shift, out_mem);
}

// Round 22
// 84.344 us; speedup vs baseline: 1.2895x; 1.0866x over previous
//
#include <hip/hip_runtime.h>
#include <hip/hip_bf16.h>

// Problem constants
#define B_SZ   16384
#define D_SZ   768
#define H_SZ   128
#define S_SZ   65536
#define E_SZ   7

// K layout: [0,768) h_t | [768,896) s_t | [896,1664) h_ctx | 1664..1666 sent | 1667 bias | pad->1696
// N layout: [0,256) r,z summed | [256,384) i_n | [384,512) h_n | [512,519) W_e | 519 W_s | pad->528
// M=16/block, 1024 blocks, 512 thr = 8 waves all-compute. Wave w: frags r=w, z=8+w, i_n=16+w,
// h_n=24+w (j in [16w,16w+16)) -> wave-local GRU; heads (frag 32) at (s mod 8)==w.
// ROUND 22: 4-step chunks, 3 LDS buffers, 2-AHEAD staging with COUNTED vmcnt + raw s_barrier
// (T3/T4): the loop never drains vmcnt to 0, so chunk DMAs ride across barriers and have a
// full compute phase to land. NT cache hints kept from r21 (W2f stays L2-resident).
#define NFR    33
#define NSTEP  53

typedef __attribute__((ext_vector_type(8))) short bf16x8;
typedef __attribute__((ext_vector_type(4))) float f32x4;
typedef __attribute__((ext_vector_type(4))) unsigned int u32x4;

#define LD4(p) (*reinterpret_cast<const float4*>(p))
#define MFMA(d, a, b) d = __builtin_amdgcn_mfma_f32_16x16x32_bf16(a, b, d, 0, 0, 0)

// async global->LDS DMA, 16B/lane (dest = wave-uniform base + lane*16); aux 2 = non-temporal
#define GLDS(gp, lp) __builtin_amdgcn_global_load_lds(                              \
        (const __attribute__((address_space(1))) unsigned int*)(gp),                \
        (__attribute__((address_space(3))) unsigned int*)(lp), 16, 0, 0)
#define GLDSN(gp, lp) __builtin_amdgcn_global_load_lds(                             \
        (const __attribute__((address_space(1))) unsigned int*)(gp),                \
        (__attribute__((address_space(3))) unsigned int*)(lp), 16, 0, 2)

// counted-vmcnt pipeline barrier: allow the newest N DMAs to stay in flight
#define PIPE_BAR(N) do {                                                            \
        asm volatile("s_waitcnt vmcnt(" #N ")" ::: "memory");                       \
        __builtin_amdgcn_sched_barrier(0);                                          \
        __builtin_amdgcn_s_barrier();                                               \
    } while (0)

static __device__ __forceinline__ ushort f2bf(float v) {
    unsigned u = __float_as_uint(v);
    u = (u + 0x7FFFu + ((u >> 16) & 1u)) >> 16;   // RNE (pack kernel / tail only)
    return (ushort)u;
}

static __device__ __forceinline__ unsigned pk2(float x, float y) {
    unsigned a = __float_as_uint(x) + 0x8000u;
    unsigned b = __float_as_uint(y) + 0x8000u;
    return __builtin_amdgcn_perm(b, a, 0x07060302);   // [a.hi16 | b.hi16]
}

static __device__ __forceinline__ bf16x8 cvt8(float4 a, float4 b) {
    union { unsigned u[4]; bf16x8 v; } r;
    r.u[0] = pk2(a.x, a.y); r.u[1] = pk2(a.z, a.w);
    r.u[2] = pk2(b.x, b.y); r.u[3] = pk2(b.z, b.w);
    return r.v;
}

// logical packed-weight value at (n, k)
static __device__ __forceinline__ float w2_value(int n, int k,
    const float* __restrict__ W_ih, const float* __restrict__ W_hh,
    const float* __restrict__ b_ih, const float* __restrict__ b_hh,
    const float* __restrict__ W_e,  const float* __restrict__ b_e,
    const float* __restrict__ W_s,  const float* __restrict__ b_s)
{
    float v = 0.0f;
    if (n < 256) {
        if (k < 768)                        v = W_ih[(size_t)n * 771 + k];
        else if (k < 896)                   v = W_hh[(size_t)n * 128 + (k - 768)];
        else if (k >= 1664 && k < 1667)     v = W_ih[(size_t)n * 771 + 768 + (k - 1664)];
        else if (k == 1667)                 v = b_ih[n] + b_hh[n];
    } else if (n < 384) {
        if (k < 768)                        v = W_ih[(size_t)n * 771 + k];
        else if (k >= 1664 && k < 1667)     v = W_ih[(size_t)n * 771 + 768 + (k - 1664)];
        else if (k == 1667)                 v = b_ih[n];
    } else if (n < 512) {
        int g = n - 128;
        if (k >= 768 && k < 896)            v = W_hh[(size_t)g * 128 + (k - 768)];
        else if (k == 1667)                 v = b_hh[g];
    } else if (n < 520) {
        int e = n - 512;
        const float* Wr = (e < E_SZ) ? (W_e + (size_t)e * 1667) : W_s;
        if (k < 768)                        v = Wr[k];
        else if (k < 896)                   v = Wr[771 + (k - 768)];
        else if (k < 1664)                  v = Wr[899 + (k - 896)];
        else if (k < 1667)                  v = Wr[768 + (k - 1664)];
        else if (k == 1667)                 v = (e < E_SZ) ? b_e[e] : b_s[0];
    }
    return v;
}

// ---------------- pack W2 frag-major: W2f[(nf*NSTEP + kstep)*64 + lane][8] ----------------
__global__ __launch_bounds__(256) void pack_w2f_kernel(
    const float* __restrict__ W_ih, const float* __restrict__ W_hh,
    const float* __restrict__ b_ih, const float* __restrict__ b_hh,
    const float* __restrict__ W_e,  const float* __restrict__ b_e,
    const float* __restrict__ W_s,  const float* __restrict__ b_s,
    ushort* __restrict__ W2f)
{
    int tid = blockIdx.x * 256 + threadIdx.x;
    if (tid >= NFR * NSTEP * 64) return;
    int lane  = tid & 63;
    int kstep = (tid >> 6) % NSTEP;
    int nf    = tid / (NSTEP * 64);
    int n     = nf * 16 + (lane & 15);
    int kbase = kstep * 32 + (lane >> 4) * 8;
    ushort o[8];
#pragma unroll
    for (int j = 0; j < 8; ++j)
        o[j] = f2bf(w2_value(n, kbase + j, W_ih, W_hh, b_ih, b_hh, W_e, b_e, W_s, b_s));
    *reinterpret_cast<uint4*>(W2f + (size_t)tid * 8) = *reinterpret_cast<const uint4*>(o);
}

// ---------------- winner (last-write-wins) ----------------
__global__ __launch_bounds__(256) void winner_kernel(const int* __restrict__ slot_ids,
                                                     int* __restrict__ winner)
{
    int b = blockIdx.x * 256 + threadIdx.x;
    if (b < B_SZ) atomicMax(&winner[slot_ids[b]], b);
}

static __device__ __forceinline__ bf16x8 ldB(const ushort* __restrict__ W2f, int nf, int ks, int lane) {
    return *reinterpret_cast<const bf16x8*>(W2f + ((size_t)(nf * NSTEP + ks) * 64 + lane) * 8);
}

// LDS A read: 4-step panel of [16 rows][128 B], XOR-swizzled (matches pre-swizzled DMA source)
static __device__ __forceinline__ float4 lds_rd(const char* Ab, int st, int row, int h) {
    return *reinterpret_cast<const float4*>(Ab + st * 2048 + row * 128 + ((h ^ (row & 7)) << 4));
}

// h_t chunk (4 steps): frags r=W, z=8+W, i_n=16+W; heads when (s&7)==W
template<int W>
static __device__ __forceinline__ void ht4(int c, const char* Ab, int lane,
                                           const ushort* __restrict__ W2f,
                                           f32x4* __restrict__ acc, f32x4* __restrict__ hacc)
{
    const int cl = lane & 15, kg = lane >> 4;
#pragma unroll
    for (int st = 0; st < 4; ++st) {
        const int s = c * 4 + st;
        bf16x8 B0 = ldB(W2f, W, s, lane), B1 = ldB(W2f, 8 + W, s, lane), B2 = ldB(W2f, 16 + W, s, lane);
        float4 x0 = lds_rd(Ab, st, cl, 2 * kg), x1 = lds_rd(Ab, st, cl, 2 * kg + 1);
        bf16x8 a0 = cvt8(x0, x1);
        MFMA(acc[0], a0, B0); MFMA(acc[1], a0, B1); MFMA(acc[2], a0, B2);
        if ((s & 7) == W) {
            bf16x8 Bh = ldB(W2f, 32, s, lane);
            MFMA(hacc[0], a0, Bh);
        }
    }
}

// s_t chunk (c=6, steps 24-27): frags r=W, z=8+W, h_n=24+W; heads at t==W (W<4)
template<int W>
static __device__ __forceinline__ void st4(const char* Ab, int lane,
                                           const ushort* __restrict__ W2f,
                                           f32x4* __restrict__ acc, f32x4* __restrict__ hacc)
{
    const int cl = lane & 15, kg = lane >> 4;
#pragma unroll
    for (int t = 0; t < 4; ++t) {
        const int s = 24 + t;
        bf16x8 B0 = ldB(W2f, W, s, lane), B1 = ldB(W2f, 8 + W, s, lane), B2 = ldB(W2f, 24 + W, s, lane);
        float4 x0 = lds_rd(Ab, t, cl, 2 * kg), x1 = lds_rd(Ab, t, cl, 2 * kg + 1);
        bf16x8 a0 = cvt8(x0, x1);
        MFMA(acc[0], a0, B0); MFMA(acc[1], a0, B1); MFMA(acc[3], a0, B2);
        if constexpr (W < 4) {
            if (t == W) {
                bf16x8 Bh = ldB(W2f, 32, s, lane);
                MFMA(hacc[0], a0, Bh);
            }
        }
    }
}

// ctx chunk (4 steps, heads only): wave W computes iff (c&1)==(W>>2), at st = W&3
template<int W>
static __device__ __forceinline__ void ctx4(int c, const char* Ab, int lane,
                                            const ushort* __restrict__ W2f,
                                            f32x4* __restrict__ hacc)
{
    if ((c & 1) == (W >> 2)) {
        const int cl = lane & 15, kg = lane >> 4;
        const int st = W & 3;
        const int s  = c * 4 + st;
        bf16x8 Bh = ldB(W2f, 32, s, lane);
        float4 x0 = lds_rd(Ab, st, cl, 2 * kg), x1 = lds_rd(Ab, st, cl, 2 * kg + 1);
        MFMA(hacc[0], cvt8(x0, x1), Bh);
    }
}

// tail step 52 + wave-local GRU epilogue
template<int W>
static __device__ __forceinline__ void tail_and_gru(
    const float* __restrict__ sent, const float* __restrict__ memory,
    const int* __restrict__ slot_ids, const int* __restrict__ winner,
    int row0, int lane, const ushort* __restrict__ W2f,
    f32x4* __restrict__ acc, f32x4* __restrict__ hacc, float* __restrict__ out_mem)
{
    const int cl = lane & 15, kg = lane >> 4;
    {
        const int rA0 = row0 + cl;
        bf16x8 a0;
#pragma unroll
        for (int jj = 0; jj < 8; ++jj) {
            int kk = kg * 8 + jj;
            float v0 = 0.f;
            if (kk < 3)       v0 = sent[(size_t)rA0 * 3 + kk];
            else if (kk == 3) v0 = 1.f;
            a0[jj] = (short)f2bf(v0);
        }
        bf16x8 T0 = ldB(W2f, W, 52, lane),      T1 = ldB(W2f, 8 + W, 52, lane);
        bf16x8 T2 = ldB(W2f, 16 + W, 52, lane), T3 = ldB(W2f, 24 + W, 52, lane);
        MFMA(acc[0], a0, T0); MFMA(acc[1], a0, T1);
        MFMA(acc[2], a0, T2); MFMA(acc[3], a0, T3);
        if constexpr (W == 4) {   // 52 & 7 == 4
            bf16x8 Bh = ldB(W2f, 32, 52, lane);
            MFMA(hacc[0], a0, Bh);
        }
    }
    const int j = 16 * W + cl;
#pragma unroll
    for (int rr = 0; rr < 4; ++rr) {
        const int row  = row0 + kg * 4 + rr;
        const int slot = slot_ids[row];
        const bool win = (winner[slot] == row);
        float rgate = acc[0][rr];
        float zg    = acc[1][rr];
        float inn   = acc[2][rr];
        float hnn   = acc[3][rr];
        rgate = 1.0f / (1.0f + __expf(-rgate));
        zg    = 1.0f / (1.0f + __expf(-zg));
        float nn = tanhf(inn + rgate * hnn);
        float h  = memory[(size_t)slot * H_SZ + j];   // exact f32 pre-update state
        float sn = (1.0f - zg) * nn + zg * h;
        if (win) out_mem[(size_t)slot * H_SZ + j] = sn;
    }
}

// ---------------- fused kernel: M=16, 3-buffer 2-ahead counted-vmcnt pipeline ----------------
__global__ __launch_bounds__(512, 8) void fused_kernel(
    const float* __restrict__ h_t,   const float* __restrict__ h_ctx,
    const float* __restrict__ sent,  const int* __restrict__ slot_ids,
    const float* __restrict__ memory,const ushort* __restrict__ W2f,
    const int* __restrict__ winner,
    float* __restrict__ out_emo, float* __restrict__ out_shift, float* __restrict__ out_mem)
{
    __shared__ alignas(16) char  A_st[3][4 * 2048];   // 24 KB: 3 bufs x 4 steps x [16 rows][128 B]
    __shared__ alignas(16) f32x4 redh[8 * 64];        // 8 KB heads partials

    const int tid  = threadIdx.x;
    const int wave = tid >> 6;
    const int lane = tid & 63;
    const int row0 = blockIdx.x * 16;

    // staging identity: wave-uniform step sst = wave>>1 (0..3); half-panel sbh = (wave&1)*1024;
    // per-lane row/chunk: srow = (wave&1)*8 + (lane>>3), source chunk pre-swizzled.
    const int sst   = wave >> 1;
    const int sbh   = (wave & 1) * 1024;
    const int srow  = (wave & 1) * 8 + (lane >> 3);
    const int scg   = (lane & 7) ^ (srow & 7);
    const int sslot = slot_ids[row0 + srow];

    f32x4 acc[4], hacc[1];
    {
        f32x4 z = {0.f, 0.f, 0.f, 0.f};
#pragma unroll
        for (int i = 0; i < 4; ++i) acc[i] = z;
        hacc[0] = z;
    }

    // stage chunk C into A_st[C%3] (1 DMA/thread); C literal -> branches fold
#define STAGE(C) do {                                                                     \
        const int s_ = 4 * (C) + sst;                                                     \
        char* dst_ = &A_st[(C) % 3][sst * 2048 + sbh];                                    \
        if (s_ < 24)      GLDSN(h_t + (size_t)(row0 + srow) * D_SZ + s_ * 32 + scg * 4, dst_); \
        else if (s_ < 28) GLDS(memory + (size_t)sslot * H_SZ + (s_ - 24) * 32 + scg * 4, dst_); \
        else              GLDSN(h_ctx + (size_t)(row0 + srow) * D_SZ + (s_ - 28) * 32 + scg * 4, dst_); \
    } while (0)

#define COPYSL(I0) do {                                                                   \
        int idx  = (I0) * 512 + tid;             /* 0..2047 over 4 slices */              \
        int rr   = idx >> 5;                     /* slot row 0..63 */                     \
        int c4   = (idx & 31) * 4;                                                        \
        int slot = blockIdx.x * 64 + rr;                                                  \
        if (winner[slot] < 0) {                                                           \
            u32x4 v = __builtin_nontemporal_load(                                         \
                reinterpret_cast<const u32x4*>(memory + (size_t)slot * H_SZ + c4));       \
            __builtin_nontemporal_store(v,                                                \
                reinterpret_cast<u32x4*>(out_mem + (size_t)slot * H_SZ + c4));            \
        } } while (0)

#define BYWAVE(...) do { switch (wave) {                                                  \
    case 0: { constexpr int W = 0; __VA_ARGS__; } break;                                  \
    case 1: { constexpr int W = 1; __VA_ARGS__; } break;                                  \
    case 2: { constexpr int W = 2; __VA_ARGS__; } break;                                  \
    case 3: { constexpr int W = 3; __VA_ARGS__; } break;                                  \
    case 4: { constexpr int W = 4; __VA_ARGS__; } break;                                  \
    case 5: { constexpr int W = 5; __VA_ARGS__; } break;                                  \
    case 6: { constexpr int W = 6; __VA_ARGS__; } break;                                  \
    default:{ constexpr int W = 7; __VA_ARGS__; } break; } } while (0)

    // prologue: stage chunks 0,1; allow chunk 1's DMA to remain in flight
    STAGE(0); STAGE(1);
    PIPE_BAR(1);

    // iters 0-5: h_t chunks (steps 0-23); 2-ahead staging; copy slices in iters 0-3
    BYWAVE(ht4<W>(0, A_st[0], lane, W2f, acc, hacc)); COPYSL(0); STAGE(2);  PIPE_BAR(1);
    BYWAVE(ht4<W>(1, A_st[1], lane, W2f, acc, hacc)); COPYSL(1); STAGE(3);  PIPE_BAR(1);
    BYWAVE(ht4<W>(2, A_st[2], lane, W2f, acc, hacc)); COPYSL(2); STAGE(4);  PIPE_BAR(1);
    BYWAVE(ht4<W>(3, A_st[0], lane, W2f, acc, hacc)); COPYSL(3); STAGE(5);  PIPE_BAR(1);
    BYWAVE(ht4<W>(4, A_st[1], lane, W2f, acc, hacc));            STAGE(6);  PIPE_BAR(1);
    BYWAVE(ht4<W>(5, A_st[2], lane, W2f, acc, hacc));            STAGE(7);  PIPE_BAR(1);
    // iter 6: s_t chunk (steps 24-27)
    BYWAVE(st4<W>(A_st[0], lane, W2f, acc, hacc));               STAGE(8);  PIPE_BAR(1);
    // iters 7-12: ctx chunks (steps 28-51)
    BYWAVE(ctx4<W>(7,  A_st[1], lane, W2f, hacc));               STAGE(9);  PIPE_BAR(1);
    BYWAVE(ctx4<W>(8,  A_st[2], lane, W2f, hacc));               STAGE(10); PIPE_BAR(1);
    BYWAVE(ctx4<W>(9,  A_st[0], lane, W2f, hacc));               STAGE(11); PIPE_BAR(1);
    BYWAVE(ctx4<W>(10, A_st[1], lane, W2f, hacc));               STAGE(12); PIPE_BAR(1);
    BYWAVE(ctx4<W>(11, A_st[2], lane, W2f, hacc));                          PIPE_BAR(0);
    BYWAVE((ctx4<W>(12, A_st[0], lane, W2f, hacc),
            tail_and_gru<W>(sent, memory, slot_ids, winner, row0, lane, W2f,
                            acc, hacc, out_mem)));

    // heads outputs: LDS reduction over 8 waves
    __syncthreads();
    redh[wave * 64 + lane] = hacc[0];
    __syncthreads();
    if (tid < 64) {
        f32x4 hv = redh[tid];
#pragma unroll
        for (int w = 1; w < 8; ++w) hv += redh[w * 64 + tid];
        const int col  = tid & 15;
        const int rowb = row0 + (tid >> 4) * 4;
#pragma unroll
        for (int rr = 0; rr < 4; ++rr) {
            const int row = rowb + rr;
            if (col < E_SZ)       out_emo[(size_t)row * E_SZ + col] = hv[rr];
            else if (col == E_SZ) out_shift[row] = hv[rr];
        }
    }
#undef STAGE
#undef COPYSL
#undef BYWAVE
}

// ---------------- launch ----------------
extern "C" void kernel_launch(void* const* d_in, const int* in_sizes, int n_in,
                              void* d_out, int out_size, void* d_ws, size_t ws_size,
                              hipStream_t stream)
{
    const float* h_t     = (const float*)d_in[0];
    const float* h_ctx   = (const float*)d_in[1];
    const float* sent    = (const float*)d_in[2];
    const int*   slot_ids= (const int*)  d_in[3];
    const float* memory  = (const float*)d_in[4];
    const float* W_ih    = (const float*)d_in[5];
    const float* W_hh    = (const float*)d_in[6];
    const float* b_ih    = (const float*)d_in[7];
    const float* b_hh    = (const float*)d_in[8];
    const float* W_e     = (const float*)d_in[9];
    const float* b_e     = (const float*)d_in[10];
    const float* W_s     = (const float*)d_in[11];
    const float* b_s     = (const float*)d_in[12];

    float* out       = (float*)d_out;
    float* out_emo   = out;                                    // [B,7]
    float* out_shift = out + (size_t)B_SZ * E_SZ;              // [B]
    float* out_mem   = out + (size_t)B_SZ * E_SZ + B_SZ;       // [S,H]

    int*    winner = (int*)d_ws;                               // S ints
    ushort* W2f    = (ushort*)((char*)d_ws + (size_t)S_SZ * sizeof(int));

    hipMemsetAsync(winner, 0xFF, (size_t)S_SZ * sizeof(int), stream);   // -1

    pack_w2f_kernel<<<(NFR * NSTEP * 64 + 255) / 256, 256, 0, stream>>>(
        W_ih, W_hh, b_ih, b_hh, W_e, b_e, W_s, b_s, W2f);
    winner_kernel<<<B_SZ / 256, 256, 0, stream>>>(slot_ids, winner);
    fused_kernel<<<B_SZ / 16, 512, 0, stream>>>(
        h_t, h_ctx, sent, slot_ids, memory, W2f, winner, out_emo, out_shift, out_mem);
}

// Round 23
// 70.135 us; speedup vs baseline: 1.5508x; 1.2026x over previous
//
#include <hip/hip_runtime.h>
#include <hip/hip_bf16.h>

// Problem constants
#define B_SZ   16384
#define D_SZ   768
#define H_SZ   128
#define S_SZ   65536
#define E_SZ   7

// K layout: [0,768) h_t | [768,896) s_t | [896,1664) h_ctx | 1664..1666 sent | 1667 bias | pad->1696
// N layout: [0,256) r,z summed | [256,384) i_n | [384,512) h_n | [512,519) W_e | 519 W_s | pad->528
// ROUND 23: M=32/block (512 blocks, 512 thr = 8 waves). Wave w: frags r=w, z=8+w, i_n=16+w,
// h_n=24+w for hidden j in [16w,16w+16), TWO rowgroups (rows cl and 16+cl) -> each B-fragment
// feeds 2 MFMAs; aggregate B L2 traffic halves to ~390 MB. 4-step chunks, 3 LDS buffers,
// 2-ahead staging (2 DMAs/thread/chunk) with counted vmcnt(2) + raw s_barrier; NT cache hints.
#define NFR    33
#define NSTEP  53

typedef __attribute__((ext_vector_type(8))) short bf16x8;
typedef __attribute__((ext_vector_type(4))) float f32x4;
typedef __attribute__((ext_vector_type(4))) unsigned int u32x4;

#define LD4(p) (*reinterpret_cast<const float4*>(p))
#define MFMA(d, a, b) d = __builtin_amdgcn_mfma_f32_16x16x32_bf16(a, b, d, 0, 0, 0)

// async global->LDS DMA, 16B/lane (dest = wave-uniform base + lane*16); aux 2 = non-temporal
#define GLDS(gp, lp) __builtin_amdgcn_global_load_lds(                              \
        (const __attribute__((address_space(1))) unsigned int*)(gp),                \
        (__attribute__((address_space(3))) unsigned int*)(lp), 16, 0, 0)
#define GLDSN(gp, lp) __builtin_amdgcn_global_load_lds(                             \
        (const __attribute__((address_space(1))) unsigned int*)(gp),                \
        (__attribute__((address_space(3))) unsigned int*)(lp), 16, 0, 2)

// counted-vmcnt pipeline barrier: allow the newest N VMEM ops to stay in flight
#define PIPE_BAR(N) do {                                                            \
        asm volatile("s_waitcnt vmcnt(" #N ")" ::: "memory");                       \
        __builtin_amdgcn_sched_barrier(0);                                          \
        __builtin_amdgcn_s_barrier();                                               \
    } while (0)

static __device__ __forceinline__ ushort f2bf(float v) {
    unsigned u = __float_as_uint(v);
    u = (u + 0x7FFFu + ((u >> 16) & 1u)) >> 16;   // RNE (pack kernel / tail only)
    return (ushort)u;
}

static __device__ __forceinline__ unsigned pk2(float x, float y) {
    unsigned a = __float_as_uint(x) + 0x8000u;
    unsigned b = __float_as_uint(y) + 0x8000u;
    return __builtin_amdgcn_perm(b, a, 0x07060302);   // [a.hi16 | b.hi16]
}

static __device__ __forceinline__ bf16x8 cvt8(float4 a, float4 b) {
    union { unsigned u[4]; bf16x8 v; } r;
    r.u[0] = pk2(a.x, a.y); r.u[1] = pk2(a.z, a.w);
    r.u[2] = pk2(b.x, b.y); r.u[3] = pk2(b.z, b.w);
    return r.v;
}

// logical packed-weight value at (n, k)
static __device__ __forceinline__ float w2_value(int n, int k,
    const float* __restrict__ W_ih, const float* __restrict__ W_hh,
    const float* __restrict__ b_ih, const float* __restrict__ b_hh,
    const float* __restrict__ W_e,  const float* __restrict__ b_e,
    const float* __restrict__ W_s,  const float* __restrict__ b_s)
{
    float v = 0.0f;
    if (n < 256) {
        if (k < 768)                        v = W_ih[(size_t)n * 771 + k];
        else if (k < 896)                   v = W_hh[(size_t)n * 128 + (k - 768)];
        else if (k >= 1664 && k < 1667)     v = W_ih[(size_t)n * 771 + 768 + (k - 1664)];
        else if (k == 1667)                 v = b_ih[n] + b_hh[n];
    } else if (n < 384) {
        if (k < 768)                        v = W_ih[(size_t)n * 771 + k];
        else if (k >= 1664 && k < 1667)     v = W_ih[(size_t)n * 771 + 768 + (k - 1664)];
        else if (k == 1667)                 v = b_ih[n];
    } else if (n < 512) {
        int g = n - 128;
        if (k >= 768 && k < 896)            v = W_hh[(size_t)g * 128 + (k - 768)];
        else if (k == 1667)                 v = b_hh[g];
    } else if (n < 520) {
        int e = n - 512;
        const float* Wr = (e < E_SZ) ? (W_e + (size_t)e * 1667) : W_s;
        if (k < 768)                        v = Wr[k];
        else if (k < 896)                   v = Wr[771 + (k - 768)];
        else if (k < 1664)                  v = Wr[899 + (k - 896)];
        else if (k < 1667)                  v = Wr[768 + (k - 1664)];
        else if (k == 1667)                 v = (e < E_SZ) ? b_e[e] : b_s[0];
    }
    return v;
}

// ---------------- pack W2 frag-major: W2f[(nf*NSTEP + kstep)*64 + lane][8] ----------------
__global__ __launch_bounds__(256) void pack_w2f_kernel(
    const float* __restrict__ W_ih, const float* __restrict__ W_hh,
    const float* __restrict__ b_ih, const float* __restrict__ b_hh,
    const float* __restrict__ W_e,  const float* __restrict__ b_e,
    const float* __restrict__ W_s,  const float* __restrict__ b_s,
    ushort* __restrict__ W2f)
{
    int tid = blockIdx.x * 256 + threadIdx.x;
    if (tid >= NFR * NSTEP * 64) return;
    int lane  = tid & 63;
    int kstep = (tid >> 6) % NSTEP;
    int nf    = tid / (NSTEP * 64);
    int n     = nf * 16 + (lane & 15);
    int kbase = kstep * 32 + (lane >> 4) * 8;
    ushort o[8];
#pragma unroll
    for (int j = 0; j < 8; ++j)
        o[j] = f2bf(w2_value(n, kbase + j, W_ih, W_hh, b_ih, b_hh, W_e, b_e, W_s, b_s));
    *reinterpret_cast<uint4*>(W2f + (size_t)tid * 8) = *reinterpret_cast<const uint4*>(o);
}

// ---------------- winner (last-write-wins) ----------------
__global__ __launch_bounds__(256) void winner_kernel(const int* __restrict__ slot_ids,
                                                     int* __restrict__ winner)
{
    int b = blockIdx.x * 256 + threadIdx.x;
    if (b < B_SZ) atomicMax(&winner[slot_ids[b]], b);
}

static __device__ __forceinline__ bf16x8 ldB(const ushort* __restrict__ W2f, int nf, int ks, int lane) {
    return *reinterpret_cast<const bf16x8*>(W2f + ((size_t)(nf * NSTEP + ks) * 64 + lane) * 8);
}

// LDS A read: 4-step panel of [32 rows][128 B], XOR-swizzled (matches pre-swizzled DMA source)
static __device__ __forceinline__ float4 lds_rd(const char* Ab, int st, int row, int h) {
    return *reinterpret_cast<const float4*>(Ab + st * 4096 + row * 128 + ((h ^ (row & 7)) << 4));
}

// h_t chunk (4 steps): frags r=W, z=8+W, i_n=16+W; two rowgroups; heads when (s&7)==W
template<int W>
static __device__ __forceinline__ void ht4(int c, const char* Ab, int lane,
                                           const ushort* __restrict__ W2f,
                                           f32x4* __restrict__ acc, f32x4* __restrict__ hacc)
{
    const int cl = lane & 15, kg = lane >> 4;
#pragma unroll
    for (int st = 0; st < 4; ++st) {
        const int s = c * 4 + st;
        bf16x8 B0 = ldB(W2f, W, s, lane), B1 = ldB(W2f, 8 + W, s, lane), B2 = ldB(W2f, 16 + W, s, lane);
        float4 x0 = lds_rd(Ab, st, cl, 2 * kg), x1 = lds_rd(Ab, st, cl, 2 * kg + 1);
        bf16x8 a0 = cvt8(x0, x1);
        MFMA(acc[0], a0, B0); MFMA(acc[1], a0, B1); MFMA(acc[2], a0, B2);
        float4 y0 = lds_rd(Ab, st, 16 + cl, 2 * kg), y1 = lds_rd(Ab, st, 16 + cl, 2 * kg + 1);
        bf16x8 a1 = cvt8(y0, y1);
        MFMA(acc[4], a1, B0); MFMA(acc[5], a1, B1); MFMA(acc[6], a1, B2);
        if ((s & 7) == W) {
            bf16x8 Bh = ldB(W2f, 32, s, lane);
            MFMA(hacc[0], a0, Bh); MFMA(hacc[1], a1, Bh);
        }
    }
}

// s_t chunk (steps 24-27): frags r=W, z=8+W, h_n=24+W; heads at t==W (W<4)
template<int W>
static __device__ __forceinline__ void st4(const char* Ab, int lane,
                                           const ushort* __restrict__ W2f,
                                           f32x4* __restrict__ acc, f32x4* __restrict__ hacc)
{
    const int cl = lane & 15, kg = lane >> 4;
#pragma unroll
    for (int t = 0; t < 4; ++t) {
        const int s = 24 + t;
        bf16x8 B0 = ldB(W2f, W, s, lane), B1 = ldB(W2f, 8 + W, s, lane), B2 = ldB(W2f, 24 + W, s, lane);
        float4 x0 = lds_rd(Ab, t, cl, 2 * kg), x1 = lds_rd(Ab, t, cl, 2 * kg + 1);
        bf16x8 a0 = cvt8(x0, x1);
        MFMA(acc[0], a0, B0); MFMA(acc[1], a0, B1); MFMA(acc[3], a0, B2);
        float4 y0 = lds_rd(Ab, t, 16 + cl, 2 * kg), y1 = lds_rd(Ab, t, 16 + cl, 2 * kg + 1);
        bf16x8 a1 = cvt8(y0, y1);
        MFMA(acc[4], a1, B0); MFMA(acc[5], a1, B1); MFMA(acc[7], a1, B2);
        if constexpr (W < 4) {
            if (t == W) {
                bf16x8 Bh = ldB(W2f, 32, s, lane);
                MFMA(hacc[0], a0, Bh); MFMA(hacc[1], a1, Bh);
            }
        }
    }
}

// ctx chunk (4 steps, heads only): wave W computes iff (c&1)==(W>>2), at st = W&3
template<int W>
static __device__ __forceinline__ void ctx4(int c, const char* Ab, int lane,
                                            const ushort* __restrict__ W2f,
                                            f32x4* __restrict__ hacc)
{
    if ((c & 1) == (W >> 2)) {
        const int cl = lane & 15, kg = lane >> 4;
        const int st = W & 3;
        const int s  = c * 4 + st;
        bf16x8 Bh = ldB(W2f, 32, s, lane);
        float4 x0 = lds_rd(Ab, st, cl, 2 * kg), x1 = lds_rd(Ab, st, cl, 2 * kg + 1);
        MFMA(hacc[0], cvt8(x0, x1), Bh);
        float4 y0 = lds_rd(Ab, st, 16 + cl, 2 * kg), y1 = lds_rd(Ab, st, 16 + cl, 2 * kg + 1);
        MFMA(hacc[1], cvt8(y0, y1), Bh);
    }
}

// tail step 52 + wave-local GRU epilogue (both rowgroups)
template<int W>
static __device__ __forceinline__ void tail_and_gru(
    const float* __restrict__ sent, const float* __restrict__ memory,
    const int* __restrict__ slot_ids, const int* __restrict__ winner,
    int row0, int lane, const ushort* __restrict__ W2f,
    f32x4* __restrict__ acc, f32x4* __restrict__ hacc, float* __restrict__ out_mem)
{
    const int cl = lane & 15, kg = lane >> 4;
    {
        const int rA0 = row0 + cl, rA1 = rA0 + 16;
        bf16x8 a0, a1;
#pragma unroll
        for (int jj = 0; jj < 8; ++jj) {
            int kk = kg * 8 + jj;
            float v0 = 0.f, v1 = 0.f;
            if (kk < 3)       { v0 = sent[(size_t)rA0 * 3 + kk]; v1 = sent[(size_t)rA1 * 3 + kk]; }
            else if (kk == 3) { v0 = 1.f; v1 = 1.f; }
            a0[jj] = (short)f2bf(v0); a1[jj] = (short)f2bf(v1);
        }
        bf16x8 T0 = ldB(W2f, W, 52, lane),      T1 = ldB(W2f, 8 + W, 52, lane);
        bf16x8 T2 = ldB(W2f, 16 + W, 52, lane), T3 = ldB(W2f, 24 + W, 52, lane);
        MFMA(acc[0], a0, T0); MFMA(acc[1], a0, T1);
        MFMA(acc[2], a0, T2); MFMA(acc[3], a0, T3);
        MFMA(acc[4], a1, T0); MFMA(acc[5], a1, T1);
        MFMA(acc[6], a1, T2); MFMA(acc[7], a1, T3);
        if constexpr (W == 4) {   // 52 & 7 == 4
            bf16x8 Bh = ldB(W2f, 32, 52, lane);
            MFMA(hacc[0], a0, Bh); MFMA(hacc[1], a1, Bh);
        }
    }
    const int j = 16 * W + cl;
#pragma unroll
    for (int rg = 0; rg < 2; ++rg) {
#pragma unroll
        for (int rr = 0; rr < 4; ++rr) {
            const int row  = row0 + rg * 16 + kg * 4 + rr;
            const int slot = slot_ids[row];
            const bool win = (winner[slot] == row);
            float rgate = acc[rg * 4 + 0][rr];
            float zg    = acc[rg * 4 + 1][rr];
            float inn   = acc[rg * 4 + 2][rr];
            float hnn   = acc[rg * 4 + 3][rr];
            rgate = 1.0f / (1.0f + __expf(-rgate));
            zg    = 1.0f / (1.0f + __expf(-zg));
            float nn = tanhf(inn + rgate * hnn);
            float h  = memory[(size_t)slot * H_SZ + j];   // exact f32 pre-update state
            float sn = (1.0f - zg) * nn + zg * h;
            if (win) out_mem[(size_t)slot * H_SZ + j] = sn;
        }
    }
}

// ---------------- fused kernel: M=32, 3-buffer 2-ahead counted-vmcnt pipeline ----------------
__global__ __launch_bounds__(512, 4) void fused_kernel(
    const float* __restrict__ h_t,   const float* __restrict__ h_ctx,
    const float* __restrict__ sent,  const int* __restrict__ slot_ids,
    const float* __restrict__ memory,const ushort* __restrict__ W2f,
    const int* __restrict__ winner,
    float* __restrict__ out_emo, float* __restrict__ out_shift, float* __restrict__ out_mem)
{
    __shared__ alignas(16) char  A_st[3][4 * 4096];   // 48 KB: 3 bufs x 4 steps x [32 rows][128 B]
    __shared__ alignas(16) f32x4 redh[2][8 * 64];     // 16 KB heads partials (2 rowgroups)

    const int tid  = threadIdx.x;
    const int wave = tid >> 6;
    const int lane = tid & 63;
    const int row0 = blockIdx.x * 32;

    // staging: wave w covers steps {w>>2, (w>>2)+2}, row-block (w&3)*8..+7.
    // dest = st*4096 + (w&3)*1024 + lane*16 (linear); source chunk pre-swizzled.
    const int sst   = wave >> 2;                 // 0/1; +2 for second DMA
    const int srb   = wave & 3;                  // row-block
    const int srow  = srb * 8 + (lane >> 3);     // 0..31
    const int scg   = (lane & 7) ^ (srow & 7);
    const int sslot = slot_ids[row0 + srow];

    f32x4 acc[8], hacc[2];
    {
        f32x4 z = {0.f, 0.f, 0.f, 0.f};
#pragma unroll
        for (int i = 0; i < 8; ++i) acc[i] = z;
        hacc[0] = z; hacc[1] = z;
    }

    // stage chunk C into A_st[C%3]: 2 DMAs/thread (steps sst and sst+2); C literal -> folds
#define STAGE(C) do { _Pragma("unroll")                                                   \
    for (int q = 0; q < 2; ++q) {                                                         \
        const int st_ = sst + 2 * q;                                                      \
        const int s_  = 4 * (C) + st_;                                                    \
        char* dst_ = &A_st[(C) % 3][st_ * 4096 + srb * 1024];                             \
        if (s_ < 24)      GLDSN(h_t + (size_t)(row0 + srow) * D_SZ + s_ * 32 + scg * 4, dst_);          \
        else if (s_ < 28) GLDS(memory + (size_t)sslot * H_SZ + (s_ - 24) * 32 + scg * 4, dst_);         \
        else              GLDSN(h_ctx + (size_t)(row0 + srow) * D_SZ + (s_ - 28) * 32 + scg * 4, dst_); \
    } } while (0)

#define COPYSL(I0) do {                                                                   \
        int idx  = (I0) * 512 + tid;             /* 0..4095 over 8 slices */              \
        int rr   = idx >> 5;                     /* slot row 0..127 */                    \
        int c4   = (idx & 31) * 4;                                                        \
        int slot = blockIdx.x * 128 + rr;                                                 \
        if (winner[slot] < 0) {                                                           \
            u32x4 v = __builtin_nontemporal_load(                                         \
                reinterpret_cast<const u32x4*>(memory + (size_t)slot * H_SZ + c4));       \
            __builtin_nontemporal_store(v,                                                \
                reinterpret_cast<u32x4*>(out_mem + (size_t)slot * H_SZ + c4));            \
        } } while (0)

#define BYWAVE(...) do { switch (wave) {                                                  \
    case 0: { constexpr int W = 0; __VA_ARGS__; } break;                                  \
    case 1: { constexpr int W = 1; __VA_ARGS__; } break;                                  \
    case 2: { constexpr int W = 2; __VA_ARGS__; } break;                                  \
    case 3: { constexpr int W = 3; __VA_ARGS__; } break;                                  \
    case 4: { constexpr int W = 4; __VA_ARGS__; } break;                                  \
    case 5: { constexpr int W = 5; __VA_ARGS__; } break;                                  \
    case 6: { constexpr int W = 6; __VA_ARGS__; } break;                                  \
    default:{ constexpr int W = 7; __VA_ARGS__; } break; } } while (0)

    // prologue: stage chunks 0,1; drain chunk 0's DMAs, keep chunk 1's 2 in flight
    STAGE(0); STAGE(1);
    PIPE_BAR(2);

    // iters 0-5: h_t chunks (steps 0-23)
    BYWAVE(ht4<W>(0, A_st[0], lane, W2f, acc, hacc)); COPYSL(0); STAGE(2);  PIPE_BAR(2);
    BYWAVE(ht4<W>(1, A_st[1], lane, W2f, acc, hacc)); COPYSL(1); STAGE(3);  PIPE_BAR(2);
    BYWAVE(ht4<W>(2, A_st[2], lane, W2f, acc, hacc)); COPYSL(2); STAGE(4);  PIPE_BAR(2);
    BYWAVE(ht4<W>(3, A_st[0], lane, W2f, acc, hacc)); COPYSL(3); STAGE(5);  PIPE_BAR(2);
    BYWAVE(ht4<W>(4, A_st[1], lane, W2f, acc, hacc)); COPYSL(4); STAGE(6);  PIPE_BAR(2);
    BYWAVE(ht4<W>(5, A_st[2], lane, W2f, acc, hacc)); COPYSL(5); STAGE(7);  PIPE_BAR(2);
    // iter 6: s_t chunk (steps 24-27)
    BYWAVE(st4<W>(A_st[0], lane, W2f, acc, hacc));    COPYSL(6); STAGE(8);  PIPE_BAR(2);
    // iters 7-12: ctx chunks (steps 28-51)
    BYWAVE(ctx4<W>(7,  A_st[1], lane, W2f, hacc));    COPYSL(7); STAGE(9);  PIPE_BAR(2);
    BYWAVE(ctx4<W>(8,  A_st[2], lane, W2f, hacc));               STAGE(10); PIPE_BAR(2);
    BYWAVE(ctx4<W>(9,  A_st[0], lane, W2f, hacc));               STAGE(11); PIPE_BAR(2);
    BYWAVE(ctx4<W>(10, A_st[1], lane, W2f, hacc));               STAGE(12); PIPE_BAR(2);
    BYWAVE(ctx4<W>(11, A_st[2], lane, W2f, hacc));                          PIPE_BAR(0);
    BYWAVE((ctx4<W>(12, A_st[0], lane, W2f, hacc),
            tail_and_gru<W>(sent, memory, slot_ids, winner, row0, lane, W2f,
                            acc, hacc, out_mem)));

    // heads outputs: LDS reduction over 8 waves, both rowgroups
    __syncthreads();
    redh[0][wave * 64 + lane] = hacc[0];
    redh[1][wave * 64 + lane] = hacc[1];
    __syncthreads();
    if (tid < 128) {
        const int rg = tid >> 6, l = tid & 63;
        f32x4 hv = redh[rg][l];
#pragma unroll
        for (int w = 1; w < 8; ++w) hv += redh[rg][w * 64 + l];
        const int col  = l & 15;
        const int rowb = row0 + rg * 16 + (l >> 4) * 4;
#pragma unroll
        for (int rr = 0; rr < 4; ++rr) {
            const int row = rowb + rr;
            if (col < E_SZ)       out_emo[(size_t)row * E_SZ + col] = hv[rr];
            else if (col == E_SZ) out_shift[row] = hv[rr];
        }
    }
#undef STAGE
#undef COPYSL
#undef BYWAVE
}

// ---------------- launch ----------------
extern "C" void kernel_launch(void* const* d_in, const int* in_sizes, int n_in,
                              void* d_out, int out_size, void* d_ws, size_t ws_size,
                              hipStream_t stream)
{
    const float* h_t     = (const float*)d_in[0];
    const float* h_ctx   = (const float*)d_in[1];
    const float* sent    = (const float*)d_in[2];
    const int*   slot_ids= (const int*)  d_in[3];
    const float* memory  = (const float*)d_in[4];
    const float* W_ih    = (const float*)d_in[5];
    const float* W_hh    = (const float*)d_in[6];
    const float* b_ih    = (const float*)d_in[7];
    const float* b_hh    = (const float*)d_in[8];
    const float* W_e     = (const float*)d_in[9];
    const float* b_e     = (const float*)d_in[10];
    const float* W_s     = (const float*)d_in[11];
    const float* b_s     = (const float*)d_in[12];

    float* out       = (float*)d_out;
    float* out_emo   = out;                                    // [B,7]
    float* out_shift = out + (size_t)B_SZ * E_SZ;              // [B]
    float* out_mem   = out + (size_t)B_SZ * E_SZ + B_SZ;       // [S,H]

    int*    winner = (int*)d_ws;                               // S ints
    ushort* W2f    = (ushort*)((char*)d_ws + (size_t)S_SZ * sizeof(int));

    hipMemsetAsync(winner, 0xFF, (size_t)S_SZ * sizeof(int), stream);   // -1

    pack_w2f_kernel<<<(NFR * NSTEP * 64 + 255) / 256, 256, 0, stream>>>(
        W_ih, W_hh, b_ih, b_hh, W_e, b_e, W_s, b_s, W2f);
    winner_kernel<<<B_SZ / 256, 256, 0, stream>>>(slot_ids, winner);
    fused_kernel<<<B_SZ / 32, 512, 0, stream>>>(
        h_t, h_ctx, sent, slot_ids, memory, W2f, winner, out_emo, out_shift, out_mem);
}